// Round 1
// baseline (66.532 us; speedup 1.0000x reference)
//
#include <hip/hip_runtime.h>

// RSA layer, last-row-only formulation.
// out[u] = softmax-weighted sum over j of fs[j,u], where
//   s[j,u] = sum_k fs[j,k] * v[k,u],   v[k,u] = w_hi[k,u] + w_dot[u]*input[k]
// (proj_hj[1023,u] and b[u] are constant in j -> cancel in softmax axis=1)
// fs[j,k] = state[k, j+1] for j<1023;  fs[1023,k] = input[k].

constexpr int U = 128;
constexpr int W = 1024;

__global__ __launch_bounds__(256) void rsa_last_kernel(
    const float* __restrict__ input,   // (128,)
    const float* __restrict__ state,   // (128,1024) row-major
    const float* __restrict__ w,       // (257,128) row-major
    float* __restrict__ out)           // (128,)
{
    const int u    = blockIdx.x;
    const int t    = threadIdx.x;
    const int lane = t & 63;
    const int wid  = t >> 6;

    __shared__ float v[U];
    __shared__ float spv[4];
    __shared__ float smax[4];
    __shared__ float ssum[4];
    __shared__ float snum[4];

    const float wdot_u = w[2 * U * U + u];

    // v[k] = w_hi[k,u] + w_dot[u]*input[k]; also reduce s[1023] = sum_k v[k]*input[k]
    float pv = 0.0f;
    if (t < U) {
        float inv = input[t];
        float vt  = fmaf(wdot_u, inv, w[t * U + u]);
        v[t] = vt;
        pv   = vt * inv;
    }
    #pragma unroll
    for (int o = 32; o > 0; o >>= 1) pv += __shfl_down(pv, o, 64);
    if (lane == 0) spv[wid] = pv;
    __syncthreads();

    // GEMM row: thread t covers state columns c = 4t..4t+3  (j = c-1).
    // Aligned float4 loads; coalesced across the wave.
    float acc0 = 0.f, acc1 = 0.f, acc2 = 0.f, acc3 = 0.f;
    const float4* sp = (const float4*)(state) + t;
    #pragma unroll 8
    for (int k = 0; k < U; ++k) {
        const float  vk = v[k];
        const float4 f  = sp[k * (W / 4)];
        acc0 = fmaf(vk, f.x, acc0);
        acc1 = fmaf(vk, f.y, acc1);
        acc2 = fmaf(vk, f.z, acc2);
        acc3 = fmaf(vk, f.w, acc3);
    }
    // thread 0, slot 0 corresponds to j=-1 (dead) -> patch in j=1023.
    if (t == 0) acc0 = spv[0] + spv[1];

    // max over all 1024 s-values
    float lm = fmaxf(fmaxf(acc0, acc1), fmaxf(acc2, acc3));
    #pragma unroll
    for (int o = 32; o > 0; o >>= 1) lm = fmaxf(lm, __shfl_down(lm, o, 64));
    if (lane == 0) smax[wid] = lm;
    __syncthreads();
    const float m = fmaxf(fmaxf(smax[0], smax[1]), fmaxf(smax[2], smax[3]));

    // fs[j,u] for this thread's j's: row u of state, cols 4t..4t+3
    float4 g = *((const float4*)(state + (size_t)u * W) + t);
    if (t == 0) g.x = input[u];   // j=1023 -> fs = input[u]

    const float e0 = __expf(acc0 - m);
    const float e1 = __expf(acc1 - m);
    const float e2 = __expf(acc2 - m);
    const float e3 = __expf(acc3 - m);
    float ls = e0 + e1 + e2 + e3;
    float ln = fmaf(g.x, e0, fmaf(g.y, e1, fmaf(g.z, e2, g.w * e3)));
    #pragma unroll
    for (int o = 32; o > 0; o >>= 1) {
        ls += __shfl_down(ls, o, 64);
        ln += __shfl_down(ln, o, 64);
    }
    if (lane == 0) { ssum[wid] = ls; snum[wid] = ln; }
    __syncthreads();

    if (t == 0) {
        const float denom = ssum[0] + ssum[1] + ssum[2] + ssum[3];
        const float numer = snum[0] + snum[1] + snum[2] + snum[3];
        out[u] = numer / denom;
    }
}

extern "C" void kernel_launch(void* const* d_in, const int* in_sizes, int n_in,
                              void* d_out, int out_size, void* d_ws, size_t ws_size,
                              hipStream_t stream) {
    const float* input = (const float*)d_in[0];   // (1,128)
    const float* state = (const float*)d_in[1];   // (128,1024)
    const float* w     = (const float*)d_in[2];   // (257,128)
    // d_in[3] = b (zeros; cancels in softmax) -- unused
    float* out = (float*)d_out;                   // (1,128)

    rsa_last_kernel<<<dim3(U), dim3(256), 0, stream>>>(input, state, w, out);
}